// Round 10
// baseline (279.557 us; speedup 1.0000x reference)
//
#include <hip/hip_runtime.h>
#include <stdint.h>

typedef __bf16 bf16x8 __attribute__((ext_vector_type(8)));
typedef float f32x4 __attribute__((ext_vector_type(4)));

// ---- workspace byte offsets ----
#define OFF_ABF   0u           // pooled as bf16, per level [8192][C]
#define OFF_GWT   62914560u    // (g*W)^T bf16 per level [512][C]
#define OFF_LOG   66846720u    // f32 [4][8192][8][16]: private partial slots (no atomics)
#define OFF_STAT  100401152u   // per (l,row): sum, sumsq  (4*8192*2 f32)
#define OFF_TEXT  100663296u   // 4096 f32 normalized text
#define OFF_U     100679680u   // 4*512 f32 (zeroed, atomic-accumulated)
#define OFF_GG    100687872u
#define OFF_BB    100696064u
#define OFF_SCAL  100704256u   // [0..3] sproto, [4..7] sqproto (zeroed)
#define WS_TOTAL  100719872u

__host__ __device__ __forceinline__ size_t abf_off(int l) {
  return (size_t)4194304u * (size_t)((1u << l) - 1u);
}
__host__ __device__ __forceinline__ size_t gwt_off(int l) {
  return (size_t)262144u * (size_t)((1u << l) - 1u);
}

__device__ __forceinline__ unsigned short f2bf(float x) {
  return (unsigned short)((__float_as_uint(x) + 0x8000u) >> 16);
}
__device__ __forceinline__ unsigned pack2(float a, float b) {
  return ((__float_as_uint(a) + 0x8000u) >> 16) |
         ((__float_as_uint(b) + 0x8000u) & 0xffff0000u);
}
__device__ __forceinline__ void async_load16(const void* g, void* l) {
  __builtin_amdgcn_global_load_lds((const __attribute__((address_space(1))) void*)g,
                                   (__attribute__((address_space(3))) void*)l,
                                   16, 0, 0);
}

struct PrepArgs {
  const float* pooled[4];
  const float* proto[4];
  const float* W[4];
  const float* g[4];
  const float* beta[4];
  const float* bias[4];
  const float* text;
  const float* lsc;
  char* ws;
};

// ---------------- aconv helpers: one 8KB unit per wave, pure TLP ----------------
__device__ __forceinline__ void loadUnit(f32x4 (&buf)[8], const f32x4* base, int lane) {
#pragma unroll
  for (int i = 0; i < 4; ++i) {
    buf[2 * i]     = base[2 * (lane + 64 * i)];
    buf[2 * i + 1] = base[2 * (lane + 64 * i) + 1];
  }
}

template <int R>
__device__ __forceinline__ void procUnit(const f32x4 (&v)[8], char* Dst, float* st,
                                         int rowBase, int lane) {
  float p1[4], p2[4];
#pragma unroll
  for (int i = 0; i < 4; ++i) {
    f32x4 a = v[2 * i], b = v[2 * i + 1];
    float s1 = ((a[0] + a[1]) + (a[2] + a[3])) + ((b[0] + b[1]) + (b[2] + b[3]));
    float s2 = 0.f;
    s2 = fmaf(a[0], a[0], s2); s2 = fmaf(a[1], a[1], s2);
    s2 = fmaf(a[2], a[2], s2); s2 = fmaf(a[3], a[3], s2);
    s2 = fmaf(b[0], b[0], s2); s2 = fmaf(b[1], b[1], s2);
    s2 = fmaf(b[2], b[2], s2); s2 = fmaf(b[3], b[3], s2);
    p1[i] = s1; p2[i] = s2;
    uint4 o = make_uint4(pack2(a[0], a[1]), pack2(a[2], a[3]),
                         pack2(b[0], b[1]), pack2(b[2], b[3]));
    *(uint4*)(Dst + 16 * (size_t)(lane + 64 * i)) = o;
  }
  if constexpr (R == 1) {
    float s1 = (p1[0] + p1[1]) + (p1[2] + p1[3]);
    float s2 = (p2[0] + p2[1]) + (p2[2] + p2[3]);
#pragma unroll
    for (int off = 1; off < 64; off <<= 1) {
      s1 += __shfl_xor(s1, off); s2 += __shfl_xor(s2, off);
    }
    if (lane == 0) {
      st[2 * (size_t)rowBase] = s1; st[2 * (size_t)rowBase + 1] = s2;
    }
  } else if constexpr (R == 2) {
#pragma unroll
    for (int h = 0; h < 2; ++h) {
      float s1 = p1[2 * h] + p1[2 * h + 1], s2 = p2[2 * h] + p2[2 * h + 1];
#pragma unroll
      for (int off = 1; off < 64; off <<= 1) {
        s1 += __shfl_xor(s1, off); s2 += __shfl_xor(s2, off);
      }
      if (lane == 0) {
        st[2 * (size_t)(rowBase + h)] = s1; st[2 * (size_t)(rowBase + h) + 1] = s2;
      }
    }
  } else if constexpr (R == 4) {
#pragma unroll
    for (int i = 0; i < 4; ++i) {
      float s1 = p1[i], s2 = p2[i];
#pragma unroll
      for (int off = 1; off < 64; off <<= 1) {
        s1 += __shfl_xor(s1, off); s2 += __shfl_xor(s2, off);
      }
      if (lane == 0) {
        st[2 * (size_t)(rowBase + i)] = s1; st[2 * (size_t)(rowBase + i) + 1] = s2;
      }
    }
  } else {  // R == 8: lanes 0-31 hold row 2i, lanes 32-63 row 2i+1
#pragma unroll
    for (int i = 0; i < 4; ++i) {
      float s1 = p1[i], s2 = p2[i];
#pragma unroll
      for (int off = 1; off < 32; off <<= 1) {
        s1 += __shfl_xor(s1, off); s2 += __shfl_xor(s2, off);
      }
      if ((lane & 31) == 0) {
        int row = rowBase + 2 * i + (lane >> 5);
        st[2 * (size_t)row] = s1; st[2 * (size_t)row + 1] = s2;
      }
    }
  }
}

// ================= prep: wtrans (bids 0..480) + aconv (bids 481..4320) merged ====
__global__ __launch_bounds__(256, 4) void prep(PrepArgs A) {
  __shared__ unsigned short tile[128][66];     // padded: 2-way-only banking
  __shared__ float redG[4][128], redB[4][128], redU[4][128];
  __shared__ float gsh[64], bsh[64], psh[64];
  __shared__ float redP[4][64];
  int t = threadIdx.x, bid = blockIdx.x;
  int w = t >> 6, lane = t & 63;

  if (bid >= 481) {
    // ---------------- aconv path ----------------
    int u0 = (bid - 481) * 4 + w;   // ONE 8KB unit per wave
    int l, uL;
    if (u0 < 8192)       { l = 3; uL = u0; }
    else if (u0 < 12288) { l = 2; uL = u0 - 8192; }
    else if (u0 < 14336) { l = 1; uL = u0 - 12288; }
    else                 { l = 0; uL = u0 - 14336; }
    const f32x4* P = (const f32x4*)A.pooled[l] + (size_t)uL * 512;
    char* Dst = A.ws + OFF_ABF + abf_off(l) + (size_t)uL * 4096;
    float* st = (float*)(A.ws + OFF_STAT) + (size_t)l * 8192 * 2;
    f32x4 v[8];
    loadUnit(v, P, lane);
    if (l == 3)      procUnit<1>(v, Dst, st, uL,     lane);
    else if (l == 2) procUnit<2>(v, Dst, st, uL * 2, lane);
    else if (l == 1) procUnit<4>(v, Dst, st, uL * 4, lane);
    else             procUnit<8>(v, Dst, st, uL * 8, lane);
    return;
  }

  if (bid == 480) {
    // ---- text l2norm: 8 rows x 512, 32 lanes/row ----
    int row = t >> 5, l32 = t & 31;
    const float* tr = A.text + row * 512 + l32;
    float v[16];
    float s = 0.f;
#pragma unroll
    for (int i = 0; i < 16; ++i) {
      v[i] = tr[32 * i];
      s = fmaf(v[i], v[i], s);
    }
#pragma unroll
    for (int off = 1; off < 32; off <<= 1) s += __shfl_xor(s, off);
    float inv = 1.0f / fmaxf(sqrtf(s), 1e-12f);
    float* tf = (float*)(A.ws + OFF_TEXT) + row * 512 + l32;
#pragma unroll
    for (int i = 0; i < 16; ++i) tf[32 * i] = v[i] * inv;
    return;
  }

  // ---------------- wtrans path (bids 0..479) ----------------
  int l, idl;
  if (bid < 256)      { l = 3; idl = bid; }
  else if (bid < 384) { l = 2; idl = bid - 256; }
  else if (bid < 448) { l = 1; idl = bid - 384; }
  else                { l = 0; idl = bid - 448; }
  int C = 256 << l;
  int sid = idl >> 2, dchunk = idl & 3;
  int j0 = sid * 64, d0 = dchunk * 128;
  bool top = (j0 < C);
  int L = lane;
  float* scal = (float*)(A.ws + OFF_SCAL);

  if (t < 64) {
    gsh[t] = A.g[l][j0 + t];
    bsh[t] = A.beta[l][j0 + t];
  }
  if (!top) {
    const float* pr = A.proto[l];
    int cb0 = j0 - C;
    float s = 0.f;
#pragma unroll
    for (int r = 0; r < 16; ++r) s += pr[(size_t)(w * 16 + r) * C + cb0 + L];
    redP[w][L] = s;
  }
  __syncthreads();
  if (!top) {
    if (t < 64) {
      float pmv = (redP[0][t] + redP[1][t] + redP[2][t] + redP[3][t]) * (1.0f / 64.0f);
      psh[t] = pmv * gsh[t];
      if (dchunk == 0) {
        float s1 = pmv, s2 = pmv * pmv;
#pragma unroll
        for (int off = 1; off < 64; off <<= 1) {
          s1 += __shfl_xor(s1, off);
          s2 += __shfl_xor(s2, off);
        }
        if (t == 0) {
          atomicAdd(&scal[l], s1);
          atomicAdd(&scal[4 + l], s2);
        }
      }
    }
    __syncthreads();
  }

  const float* W = A.W[l];
  float2 v[16];
#pragma unroll
  for (int r = 0; r < 16; ++r) {
    int j = j0 + w * 16 + r;
    v[r] = *(const float2*)(W + (size_t)j * 512 + d0 + 2 * L);
  }
  float gp0 = 0.f, gp1 = 0.f, bp0 = 0.f, bp1 = 0.f, up0 = 0.f, up1 = 0.f;
#pragma unroll
  for (int r = 0; r < 16; ++r) {
    int jl = w * 16 + r;
    float g = gsh[jl], b = bsh[jl];
    gp0 = fmaf(g, v[r].x, gp0); gp1 = fmaf(g, v[r].y, gp1);
    bp0 = fmaf(b, v[r].x, bp0); bp1 = fmaf(b, v[r].y, bp1);
    if (top) {
      tile[2 * L][jl] = f2bf(g * v[r].x);
      tile[2 * L + 1][jl] = f2bf(g * v[r].y);
    } else {
      float p = psh[jl];
      up0 = fmaf(p, v[r].x, up0); up1 = fmaf(p, v[r].y, up1);
    }
  }
  redG[w][2 * L] = gp0; redG[w][2 * L + 1] = gp1;
  redB[w][2 * L] = bp0; redB[w][2 * L + 1] = bp1;
  if (!top) { redU[w][2 * L] = up0; redU[w][2 * L + 1] = up1; }
  __syncthreads();

  if (t < 128) {
    int d = l * 512 + d0 + t;
    float G = redG[0][t] + redG[1][t] + redG[2][t] + redG[3][t];
    float B = redB[0][t] + redB[1][t] + redB[2][t] + redB[3][t];
    atomicAdd(&((float*)(A.ws + OFF_GG))[d], G);
    atomicAdd(&((float*)(A.ws + OFF_BB))[d], B);
    if (!top) {
      float U = redU[0][t] + redU[1][t] + redU[2][t] + redU[3][t];
      atomicAdd(&((float*)(A.ws + OFF_U))[d], U);
    }
  }
  if (top) {
    unsigned short* gwT = (unsigned short*)(A.ws + OFF_GWT + gwt_off(l));
    int d = t >> 1, jh = (t & 1) * 32;
    const unsigned* trow = (const unsigned*)&tile[d][jh];  // 4B-aligned
    uint4 q0 = make_uint4(trow[0], trow[1], trow[2], trow[3]);
    uint4 q1 = make_uint4(trow[4], trow[5], trow[6], trow[7]);
    uint4 q2 = make_uint4(trow[8], trow[9], trow[10], trow[11]);
    uint4 q3 = make_uint4(trow[12], trow[13], trow[14], trow[15]);
    uint4* dst = (uint4*)(gwT + (size_t)(d0 + d) * C + j0 + jh);
    dst[0] = q0; dst[1] = q1; dst[2] = q2; dst[3] = q3;
  }
}

// ================= gemm2: BK=64 (half the barrier drains), balanced XCD, swizzled ==
// R9 state: conflicts 0, FETCH minimal, 894 TF = the 128²/2-barrier/BK=32
// structure's documented ceiling. m233: ~72% of the 2-phase critical path is
// stage+vmcnt+barrier -> halve the drain count via BK 32->64 at constant
// traffic. LDS: A[128][64]bf16 16K + B 16K + misc = 38.5K (4 blocks/CU).
// Swizzle generalizes to 128B rows: granule g of row r sits in slot g^(r&7);
// DMA keeps a linear dest (rule #21) with pre-swizzled SOURCE granule; reads
// use the matching XOR (constant per lane since (row+16)&7 == row&7).
struct G2Args {
  char* ws;
  const float* bias[4];
};

__global__ __launch_bounds__(256, 3) void gemm2(G2Args A) {
  __shared__ __align__(16) char lds[39424];
  char* ws = A.ws;
  int t = threadIdx.x;
  int xcd = blockIdx.x & 7;        // round-robin XCD assumption (perf-only)
  int j   = blockIdx.x >> 3;       // 0..127 within this XCD's share
  int l   = 3 - (j >> 5);          // 32 blocks of each level per XCD (balanced)
  int jj  = j & 31;
  int rb  = xcd * 8 + (jj >> 2);
  int cb  = jj & 3;
  int C = 256 << l;
  int m0 = rb * 128, n0 = cb * 128;

  float* uArr  = (float*)(lds + 32768);
  float* gArr  = (float*)(lds + 33280);
  float* bArr  = (float*)(lds + 33792);
  float* rowM  = (float*)(lds + 34304);
  float* rowIS = (float*)(lds + 34816);
  float* textL = (float*)(lds + 35328);   // [8][128]
  const float* scal = (const float*)(ws + OFF_SCAL);

  if (t < 128) {
    int idx = l * 512 + n0 + t;
    uArr[t] = ((const float*)(ws + OFF_U))[idx];
    gArr[t] = ((const float*)(ws + OFF_GG))[idx];
    bArr[t] = ((const float*)(ws + OFF_BB))[idx] + A.bias[l][n0 + t];
  } else {
    int r = t - 128;
    const float* st = (const float*)(ws + OFF_STAT) + (size_t)(l * 8192 + m0 + r) * 2;
    float s1 = st[0], s2 = st[1];
    float inv2C = 1.0f / (float)(2 * C);
    float mr = (s1 + scal[l]) * inv2C;
    float var = (s2 + scal[4 + l]) * inv2C - mr * mr;
    rowM[r] = mr;
    rowIS[r] = rsqrtf(var + 1e-5f);
  }
  {
    const float* tf = (const float*)(ws + OFF_TEXT);
#pragma unroll
    for (int i = 0; i < 4; ++i) {
      int idx = t + 256 * i;          // 0..1023 -> [8][128]
      textL[idx] = tf[(idx >> 7) * 512 + n0 + (idx & 127)];
    }
  }

  int w = t >> 6, lane = t & 63, quad = lane >> 4, lc = lane & 15;
  const char* Abf = ws + OFF_ABF + abf_off(l);
  const char* Bw  = ws + OFF_GWT + gwt_off(l);
  const char* aP[4]; const char* bP[4];
  char* aD[4]; char* bD[4];
#pragma unroll
  for (int i = 0; i < 4; ++i) {
    int li = i * 256 + t;            // 0..1023
    int rr = li >> 3, s = li & 7;    // row 0..127, granule 0..7
    int sw = s ^ (rr & 7);           // pre-swizzled source granule
    aP[i] = Abf + ((size_t)(m0 + rr) * C + sw * 8) * 2;
    bP[i] = Bw  + ((size_t)(n0 + rr) * C + sw * 8) * 2;
    aD[i] = lds + i * 4096 + w * 1024;            // linear dest (lane*16 implicit)
    bD[i] = lds + 16384 + i * 4096 + w * 1024;
  }
  int wr = (w >> 1) * 64, wc = (w & 1) * 64;
  int arow = wr + lc, brow = wc + lc;
  int am = arow & 7, bm = brow & 7;
  const char* aF0 = lds + arow * 128 + ((quad)     ^ am) * 16;
  const char* aF1 = lds + arow * 128 + ((quad + 4) ^ am) * 16;
  const char* bF0 = lds + 16384 + brow * 128 + ((quad)     ^ bm) * 16;
  const char* bF1 = lds + 16384 + brow * 128 + ((quad + 4) ^ bm) * 16;

  f32x4 acc[4][4] = {};
  for (int k0 = 0; k0 < C; k0 += 64) {
#pragma unroll
    for (int i = 0; i < 4; ++i) {
      async_load16(aP[i], aD[i]);
      async_load16(bP[i], bD[i]);
      aP[i] += 128; bP[i] += 128;
    }
    __syncthreads();
    bf16x8 av[4];
    // K-half 0 (cols k0..k0+31)
#pragma unroll
    for (int rt = 0; rt < 4; ++rt) av[rt] = *(const bf16x8*)(aF0 + rt * 2048);
#pragma unroll
    for (int ct = 0; ct < 4; ++ct) {
      bf16x8 bv = *(const bf16x8*)(bF0 + ct * 2048);
#pragma unroll
      for (int rt = 0; rt < 4; ++rt)
        acc[rt][ct] = __builtin_amdgcn_mfma_f32_16x16x32_bf16(av[rt], bv, acc[rt][ct], 0, 0, 0);
    }
    // K-half 1 (cols k0+32..k0+63)
#pragma unroll
    for (int rt = 0; rt < 4; ++rt) av[rt] = *(const bf16x8*)(aF1 + rt * 2048);
#pragma unroll
    for (int ct = 0; ct < 4; ++ct) {
      bf16x8 bv = *(const bf16x8*)(bF1 + ct * 2048);
#pragma unroll
      for (int rt = 0; rt < 4; ++rt)
        acc[rt][ct] = __builtin_amdgcn_mfma_f32_16x16x32_bf16(av[rt], bv, acc[rt][ct], 0, 0, 0);
    }
    __syncthreads();
  }

  // epilogue: h = relu((acc + u - m*G)*invs + B); partial text dots + ||h||^2
  // slot = cb*2 + (w&1): this wave's col-half is private -> plain stores.
  int slot = cb * 2 + (w & 1);
#pragma unroll
  for (int rt = 0; rt < 4; ++rt) {
#pragma unroll
    for (int reg = 0; reg < 4; ++reg) {
      int ml = wr + rt * 16 + quad * 4 + reg;
      float rm = rowM[ml], ris = rowIS[ml];
      float p[9] = {};
#pragma unroll
      for (int ct = 0; ct < 4; ++ct) {
        int nl = wc + ct * 16 + lc;
        float h = fmaf(acc[rt][ct][reg] + uArr[nl] - rm * gArr[nl], ris, bArr[nl]);
        h = fmaxf(h, 0.f);
        p[8] = fmaf(h, h, p[8]);
#pragma unroll
        for (int k = 0; k < 8; ++k)
          p[k] = fmaf(h, textL[k * 128 + nl], p[k]);
      }
#pragma unroll
      for (int off = 1; off < 16; off <<= 1) {
#pragma unroll
        for (int k = 0; k < 9; ++k) p[k] += __shfl_xor(p[k], off);
      }
      if (lc == 0) {
        float* Lg = (float*)(ws + OFF_LOG) +
                    ((((size_t)l * 8192 + m0 + ml) * 8 + slot) << 4);
#pragma unroll
        for (int k = 0; k < 9; ++k) Lg[k] = p[k];
      }
    }
  }
}

// ================= finishK: one wave per row (2048 blocks), shfl-reduce slots ====
// R9 version had 256 blocks = 1/CU = 4 waves/CU, latency-bound on 16.8MB of
// scattered reads. Now: wave = row; lane = (s,k) = (lane>>3, lane&7); each lane
// loads its slot's dot-part + nsq, reduces over s via 3 shfl_xor steps.
__global__ __launch_bounds__(256) void finishK(const char* ws, const float* lsc,
                                               float* out) {
  int t = threadIdx.x, wv = t >> 6, lane = t & 63;
  int row = blockIdx.x * 4 + wv;
  int s = lane >> 3, k = lane & 7;
  float scale = fmaxf(lsc[0], 1e-4f) * 0.04419417382415922f;  // 1/sqrt(512)
  float x[4];
#pragma unroll
  for (int l = 0; l < 4; ++l) {
    const float* Lg = (const float*)(ws + OFF_LOG) + (((size_t)l * 8192 + row) << 7);
    float d = Lg[s * 16 + k];
    float n = Lg[s * 16 + 8];
#pragma unroll
    for (int off = 8; off < 64; off <<= 1) {
      d += __shfl_xor(d, off);
      n += __shfl_xor(n, off);
    }
    x[l] = d * (scale / fmaxf(sqrtf(n), 1e-12f));
  }
  if (s == 0) {  // lanes 0..7 hold the reduced values for k=0..7
    float mx = fmaxf(fmaxf(x[0], x[1]), fmaxf(x[2], x[3]));
    float e0 = __expf(x[0] - mx), e1 = __expf(x[1] - mx);
    float e2 = __expf(x[2] - mx), e3 = __expf(x[3] - mx);
    float inv = 1.0f / (e0 + e1 + e2 + e3);
    ((float4*)out)[(size_t)row * 8 + k] = make_float4(e0 * inv, e1 * inv, e2 * inv, e3 * inv);
  }
}

extern "C" void kernel_launch(void* const* d_in, const int* in_sizes, int n_in,
                              void* d_out, int out_size, void* d_ws, size_t ws_size,
                              hipStream_t stream) {
  (void)n_in; (void)out_size;
  if (ws_size < (size_t)WS_TOTAL) return;  // loud failure: output stays poisoned
  char* ws = (char*)d_ws;
  bool dict = (in_sizes[1] == 64 * 256);
  PrepArgs pa;
  for (int l = 0; l < 4; ++l) {
    if (dict) {
      pa.pooled[l] = (const float*)d_in[6 * l + 0];
      pa.proto[l]  = (const float*)d_in[6 * l + 1];
      pa.g[l]      = (const float*)d_in[6 * l + 2];
      pa.beta[l]   = (const float*)d_in[6 * l + 3];
      pa.W[l]      = (const float*)d_in[6 * l + 4];
      pa.bias[l]   = (const float*)d_in[6 * l + 5];
    } else {
      pa.pooled[l] = (const float*)d_in[l];
      pa.proto[l]  = (const float*)d_in[4 + l];
      pa.g[l]      = (const float*)d_in[8 + l];
      pa.beta[l]   = (const float*)d_in[12 + l];
      pa.W[l]      = (const float*)d_in[16 + l];
      pa.bias[l]   = (const float*)d_in[20 + l];
    }
  }
  pa.text = (const float*)d_in[24];
  pa.lsc = (const float*)d_in[25];
  pa.ws = ws;

  // zero the atomic accumulators (U/GG/BB/SCAL; LOG needs no zeroing — all
  // slots are fully written by exactly one producer)
  hipMemsetAsync(ws + OFF_U, 0, 3 * 8192 + 256, stream);

  prep<<<4321, 256, 0, stream>>>(pa);

  G2Args g2;
  g2.ws = ws;
  for (int l = 0; l < 4; ++l) g2.bias[l] = pa.bias[l];
  gemm2<<<1024, 256, 0, stream>>>(g2);
  finishK<<<2048, 256, 0, stream>>>(ws, pa.lsc, (float*)d_out);
}

// Round 11
// 277.361 us; speedup vs baseline: 1.0079x; 1.0079x over previous
//
#include <hip/hip_runtime.h>
#include <stdint.h>

typedef __bf16 bf16x8 __attribute__((ext_vector_type(8)));
typedef float f32x4 __attribute__((ext_vector_type(4)));

// ---- workspace byte offsets ----
#define OFF_ABF   0u           // pooled as bf16, per level [8192][C]
#define OFF_GWT   62914560u    // (g*W)^T bf16 per level [512][C]
#define OFF_LOG   66846720u    // f32 [4][8192][8][16]: private partial slots (no atomics)
#define OFF_STAT  100401152u   // per (l,row): sum, sumsq  (4*8192*2 f32)
#define OFF_TEXT  100663296u   // 4096 f32 normalized text
#define OFF_U     100679680u   // 4*512 f32 (zeroed, atomic-accumulated)
#define OFF_GG    100687872u
#define OFF_BB    100696064u
#define OFF_SCAL  100704256u   // [0..3] sproto, [4..7] sqproto (zeroed)
#define WS_TOTAL  100719872u

__host__ __device__ __forceinline__ size_t abf_off(int l) {
  return (size_t)4194304u * (size_t)((1u << l) - 1u);
}
__host__ __device__ __forceinline__ size_t gwt_off(int l) {
  return (size_t)262144u * (size_t)((1u << l) - 1u);
}

__device__ __forceinline__ unsigned short f2bf(float x) {
  return (unsigned short)((__float_as_uint(x) + 0x8000u) >> 16);
}
__device__ __forceinline__ unsigned pack2(float a, float b) {
  return ((__float_as_uint(a) + 0x8000u) >> 16) |
         ((__float_as_uint(b) + 0x8000u) & 0xffff0000u);
}
__device__ __forceinline__ void async_load16(const void* g, void* l) {
  __builtin_amdgcn_global_load_lds((const __attribute__((address_space(1))) void*)g,
                                   (__attribute__((address_space(3))) void*)l,
                                   16, 0, 0);
}

struct PrepArgs {
  const float* pooled[4];
  const float* proto[4];
  const float* W[4];
  const float* g[4];
  const float* beta[4];
  const float* bias[4];
  const float* text;
  const float* lsc;
  char* ws;
};

// ---------------- aconv helpers: one 8KB unit per wave, pure TLP ----------------
__device__ __forceinline__ void loadUnit(f32x4 (&buf)[8], const f32x4* base, int lane) {
#pragma unroll
  for (int i = 0; i < 4; ++i) {
    buf[2 * i]     = base[2 * (lane + 64 * i)];
    buf[2 * i + 1] = base[2 * (lane + 64 * i) + 1];
  }
}

template <int R>
__device__ __forceinline__ void procUnit(const f32x4 (&v)[8], char* Dst, float* st,
                                         int rowBase, int lane) {
  float p1[4], p2[4];
#pragma unroll
  for (int i = 0; i < 4; ++i) {
    f32x4 a = v[2 * i], b = v[2 * i + 1];
    float s1 = ((a[0] + a[1]) + (a[2] + a[3])) + ((b[0] + b[1]) + (b[2] + b[3]));
    float s2 = 0.f;
    s2 = fmaf(a[0], a[0], s2); s2 = fmaf(a[1], a[1], s2);
    s2 = fmaf(a[2], a[2], s2); s2 = fmaf(a[3], a[3], s2);
    s2 = fmaf(b[0], b[0], s2); s2 = fmaf(b[1], b[1], s2);
    s2 = fmaf(b[2], b[2], s2); s2 = fmaf(b[3], b[3], s2);
    p1[i] = s1; p2[i] = s2;
    uint4 o = make_uint4(pack2(a[0], a[1]), pack2(a[2], a[3]),
                         pack2(b[0], b[1]), pack2(b[2], b[3]));
    *(uint4*)(Dst + 16 * (size_t)(lane + 64 * i)) = o;
  }
  if constexpr (R == 1) {
    float s1 = (p1[0] + p1[1]) + (p1[2] + p1[3]);
    float s2 = (p2[0] + p2[1]) + (p2[2] + p2[3]);
#pragma unroll
    for (int off = 1; off < 64; off <<= 1) {
      s1 += __shfl_xor(s1, off); s2 += __shfl_xor(s2, off);
    }
    if (lane == 0) {
      st[2 * (size_t)rowBase] = s1; st[2 * (size_t)rowBase + 1] = s2;
    }
  } else if constexpr (R == 2) {
#pragma unroll
    for (int h = 0; h < 2; ++h) {
      float s1 = p1[2 * h] + p1[2 * h + 1], s2 = p2[2 * h] + p2[2 * h + 1];
#pragma unroll
      for (int off = 1; off < 64; off <<= 1) {
        s1 += __shfl_xor(s1, off); s2 += __shfl_xor(s2, off);
      }
      if (lane == 0) {
        st[2 * (size_t)(rowBase + h)] = s1; st[2 * (size_t)(rowBase + h) + 1] = s2;
      }
    }
  } else if constexpr (R == 4) {
#pragma unroll
    for (int i = 0; i < 4; ++i) {
      float s1 = p1[i], s2 = p2[i];
#pragma unroll
      for (int off = 1; off < 64; off <<= 1) {
        s1 += __shfl_xor(s1, off); s2 += __shfl_xor(s2, off);
      }
      if (lane == 0) {
        st[2 * (size_t)(rowBase + i)] = s1; st[2 * (size_t)(rowBase + i) + 1] = s2;
      }
    }
  } else {  // R == 8: lanes 0-31 hold row 2i, lanes 32-63 row 2i+1
#pragma unroll
    for (int i = 0; i < 4; ++i) {
      float s1 = p1[i], s2 = p2[i];
#pragma unroll
      for (int off = 1; off < 32; off <<= 1) {
        s1 += __shfl_xor(s1, off); s2 += __shfl_xor(s2, off);
      }
      if ((lane & 31) == 0) {
        int row = rowBase + 2 * i + (lane >> 5);
        st[2 * (size_t)row] = s1; st[2 * (size_t)row + 1] = s2;
      }
    }
  }
}

// ================= prep: wtrans (bids 0..480) + aconv (bids 481..4320) merged ====
__global__ __launch_bounds__(256, 4) void prep(PrepArgs A) {
  __shared__ unsigned short tile[128][66];     // padded: 2-way-only banking
  __shared__ float redG[4][128], redB[4][128], redU[4][128];
  __shared__ float gsh[64], bsh[64], psh[64];
  __shared__ float redP[4][64];
  int t = threadIdx.x, bid = blockIdx.x;
  int w = t >> 6, lane = t & 63;

  if (bid >= 481) {
    // ---------------- aconv path ----------------
    int u0 = (bid - 481) * 4 + w;   // ONE 8KB unit per wave
    int l, uL;
    if (u0 < 8192)       { l = 3; uL = u0; }
    else if (u0 < 12288) { l = 2; uL = u0 - 8192; }
    else if (u0 < 14336) { l = 1; uL = u0 - 12288; }
    else                 { l = 0; uL = u0 - 14336; }
    const f32x4* P = (const f32x4*)A.pooled[l] + (size_t)uL * 512;
    char* Dst = A.ws + OFF_ABF + abf_off(l) + (size_t)uL * 4096;
    float* st = (float*)(A.ws + OFF_STAT) + (size_t)l * 8192 * 2;
    f32x4 v[8];
    loadUnit(v, P, lane);
    if (l == 3)      procUnit<1>(v, Dst, st, uL,     lane);
    else if (l == 2) procUnit<2>(v, Dst, st, uL * 2, lane);
    else if (l == 1) procUnit<4>(v, Dst, st, uL * 4, lane);
    else             procUnit<8>(v, Dst, st, uL * 8, lane);
    return;
  }

  if (bid == 480) {
    // ---- text l2norm: 8 rows x 512, 32 lanes/row ----
    int row = t >> 5, l32 = t & 31;
    const float* tr = A.text + row * 512 + l32;
    float v[16];
    float s = 0.f;
#pragma unroll
    for (int i = 0; i < 16; ++i) {
      v[i] = tr[32 * i];
      s = fmaf(v[i], v[i], s);
    }
#pragma unroll
    for (int off = 1; off < 32; off <<= 1) s += __shfl_xor(s, off);
    float inv = 1.0f / fmaxf(sqrtf(s), 1e-12f);
    float* tf = (float*)(A.ws + OFF_TEXT) + row * 512 + l32;
#pragma unroll
    for (int i = 0; i < 16; ++i) tf[32 * i] = v[i] * inv;
    return;
  }

  // ---------------- wtrans path (bids 0..479) ----------------
  int l, idl;
  if (bid < 256)      { l = 3; idl = bid; }
  else if (bid < 384) { l = 2; idl = bid - 256; }
  else if (bid < 448) { l = 1; idl = bid - 384; }
  else                { l = 0; idl = bid - 448; }
  int C = 256 << l;
  int sid = idl >> 2, dchunk = idl & 3;
  int j0 = sid * 64, d0 = dchunk * 128;
  bool top = (j0 < C);
  int L = lane;
  float* scal = (float*)(A.ws + OFF_SCAL);

  if (t < 64) {
    gsh[t] = A.g[l][j0 + t];
    bsh[t] = A.beta[l][j0 + t];
  }
  if (!top) {
    const float* pr = A.proto[l];
    int cb0 = j0 - C;
    float s = 0.f;
#pragma unroll
    for (int r = 0; r < 16; ++r) s += pr[(size_t)(w * 16 + r) * C + cb0 + L];
    redP[w][L] = s;
  }
  __syncthreads();
  if (!top) {
    if (t < 64) {
      float pmv = (redP[0][t] + redP[1][t] + redP[2][t] + redP[3][t]) * (1.0f / 64.0f);
      psh[t] = pmv * gsh[t];
      if (dchunk == 0) {
        float s1 = pmv, s2 = pmv * pmv;
#pragma unroll
        for (int off = 1; off < 64; off <<= 1) {
          s1 += __shfl_xor(s1, off);
          s2 += __shfl_xor(s2, off);
        }
        if (t == 0) {
          atomicAdd(&scal[l], s1);
          atomicAdd(&scal[4 + l], s2);
        }
      }
    }
    __syncthreads();
  }

  const float* W = A.W[l];
  float2 v[16];
#pragma unroll
  for (int r = 0; r < 16; ++r) {
    int j = j0 + w * 16 + r;
    v[r] = *(const float2*)(W + (size_t)j * 512 + d0 + 2 * L);
  }
  float gp0 = 0.f, gp1 = 0.f, bp0 = 0.f, bp1 = 0.f, up0 = 0.f, up1 = 0.f;
#pragma unroll
  for (int r = 0; r < 16; ++r) {
    int jl = w * 16 + r;
    float g = gsh[jl], b = bsh[jl];
    gp0 = fmaf(g, v[r].x, gp0); gp1 = fmaf(g, v[r].y, gp1);
    bp0 = fmaf(b, v[r].x, bp0); bp1 = fmaf(b, v[r].y, bp1);
    if (top) {
      tile[2 * L][jl] = f2bf(g * v[r].x);
      tile[2 * L + 1][jl] = f2bf(g * v[r].y);
    } else {
      float p = psh[jl];
      up0 = fmaf(p, v[r].x, up0); up1 = fmaf(p, v[r].y, up1);
    }
  }
  redG[w][2 * L] = gp0; redG[w][2 * L + 1] = gp1;
  redB[w][2 * L] = bp0; redB[w][2 * L + 1] = bp1;
  if (!top) { redU[w][2 * L] = up0; redU[w][2 * L + 1] = up1; }
  __syncthreads();

  if (t < 128) {
    int d = l * 512 + d0 + t;
    float G = redG[0][t] + redG[1][t] + redG[2][t] + redG[3][t];
    float B = redB[0][t] + redB[1][t] + redB[2][t] + redB[3][t];
    atomicAdd(&((float*)(A.ws + OFF_GG))[d], G);
    atomicAdd(&((float*)(A.ws + OFF_BB))[d], B);
    if (!top) {
      float U = redU[0][t] + redU[1][t] + redU[2][t] + redU[3][t];
      atomicAdd(&((float*)(A.ws + OFF_U))[d], U);
    }
  }
  if (top) {
    unsigned short* gwT = (unsigned short*)(A.ws + OFF_GWT + gwt_off(l));
    int d = t >> 1, jh = (t & 1) * 32;
    const unsigned* trow = (const unsigned*)&tile[d][jh];  // 4B-aligned
    uint4 q0 = make_uint4(trow[0], trow[1], trow[2], trow[3]);
    uint4 q1 = make_uint4(trow[4], trow[5], trow[6], trow[7]);
    uint4 q2 = make_uint4(trow[8], trow[9], trow[10], trow[11]);
    uint4 q3 = make_uint4(trow[12], trow[13], trow[14], trow[15]);
    uint4* dst = (uint4*)(gwT + (size_t)(d0 + d) * C + j0 + jh);
    dst[0] = q0; dst[1] = q1; dst[2] = q2; dst[3] = q3;
  }
}

// ================= gemm2: 2-phase double-buffer (T3/T4 minimum), balanced XCD ====
// R10 lesson: BK growth halves barrier COUNT but not drain PLACEMENT — the
// structure STAGE -> barrier(vmcnt0) -> compute exposes full load latency every
// step. Fix: dbuf. Per step: STAGE(buf[nxt], k+1) -> ds_read+MFMA on buf[cur]
// -> ONE barrier. The barrier's compiler-inserted vmcnt(0) now drains loads
// issued BEFORE ~180cy of compute. Race-free: buf[nxt] last read in step k-1,
// ordered by that step's barrier. BK=32, dbuf 32KB + misc = 39.4KB, 4 blk/CU.
// Swizzle (verified 0-conflict): source granule kq^((row>>1)&3), read
// slot quad^((row>>1)&3). Balanced XCD map (R8): 32 blocks of each level/XCD.
struct G2Args {
  char* ws;
  const float* bias[4];
};

__global__ __launch_bounds__(256, 4) void gemm2(G2Args A) {
  __shared__ __align__(16) char lds[39424];   // dbuf 2x(A 8K | B 8K) | misc
  char* ws = A.ws;
  int t = threadIdx.x;
  int xcd = blockIdx.x & 7;        // round-robin XCD assumption (perf-only)
  int j   = blockIdx.x >> 3;       // 0..127 within this XCD's share
  int l   = 3 - (j >> 5);          // 32 blocks of each level per XCD (balanced)
  int jj  = j & 31;
  int rb  = xcd * 8 + (jj >> 2);
  int cb  = jj & 3;
  int C = 256 << l;
  int nst = C >> 5;
  int m0 = rb * 128, n0 = cb * 128;

  float* uArr  = (float*)(lds + 32768);
  float* gArr  = (float*)(lds + 33280);
  float* bArr  = (float*)(lds + 33792);
  float* rowM  = (float*)(lds + 34304);
  float* rowIS = (float*)(lds + 34816);
  float* textL = (float*)(lds + 35328);   // [8][128]
  const float* scal = (const float*)(ws + OFF_SCAL);

  if (t < 128) {
    int idx = l * 512 + n0 + t;
    uArr[t] = ((const float*)(ws + OFF_U))[idx];
    gArr[t] = ((const float*)(ws + OFF_GG))[idx];
    bArr[t] = ((const float*)(ws + OFF_BB))[idx] + A.bias[l][n0 + t];
  } else {
    int r = t - 128;
    const float* st = (const float*)(ws + OFF_STAT) + (size_t)(l * 8192 + m0 + r) * 2;
    float s1 = st[0], s2 = st[1];
    float inv2C = 1.0f / (float)(2 * C);
    float mr = (s1 + scal[l]) * inv2C;
    float var = (s2 + scal[4 + l]) * inv2C - mr * mr;
    rowM[r] = mr;
    rowIS[r] = rsqrtf(var + 1e-5f);
  }
  {
    const float* tf = (const float*)(ws + OFF_TEXT);
#pragma unroll
    for (int i = 0; i < 4; ++i) {
      int idx = t + 256 * i;          // 0..1023 -> [8][128]
      textL[idx] = tf[(idx >> 7) * 512 + n0 + (idx & 127)];
    }
  }

  int w = t >> 6, lane = t & 63, quad = lane >> 4, lc = lane & 15;
  const char* Abf = ws + OFF_ABF + abf_off(l);
  const char* Bw  = ws + OFF_GWT + gwt_off(l);
  const char* aP[2]; const char* bP[2];
  int aO[2], bO[2];
#pragma unroll
  for (int i = 0; i < 2; ++i) {
    int li = i * 256 + t;
    int rr = li >> 2, kq = li & 3;
    int sw = kq ^ ((rr >> 1) & 3);          // pre-swizzled source granule
    aP[i] = Abf + ((size_t)(m0 + rr) * C + sw * 8) * 2;
    bP[i] = Bw  + ((size_t)(n0 + rr) * C + sw * 8) * 2;
    aO[i] = i * 4096 + w * 1024;            // within-buffer offsets (lane*16 implicit)
    bO[i] = 8192 + i * 4096 + w * 1024;
  }
  int wr = (w >> 1) * 64, wc = (w & 1) * 64;
  int arow = wr + lc, brow = wc + lc;
  int aFo = arow * 64 + (quad ^ ((arow >> 1) & 3)) * 16;
  int bFo = 8192 + brow * 64 + (quad ^ ((brow >> 1) & 3)) * 16;

  // prologue: stage k=0 into buf0; barrier drains it
  async_load16(aP[0], lds + aO[0]); async_load16(aP[1], lds + aO[1]);
  async_load16(bP[0], lds + bO[0]); async_load16(bP[1], lds + bO[1]);
  aP[0] += 64; aP[1] += 64; bP[0] += 64; bP[1] += 64;
  __syncthreads();

  f32x4 acc[4][4] = {};
  for (int k = 0; k < nst; ++k) {
    int cur = k & 1;
    char* nb = lds + (cur ^ 1) * 16384;
    if (k + 1 < nst) {   // stage NEXT tile — drains at the END-of-step barrier
      async_load16(aP[0], nb + aO[0]); async_load16(aP[1], nb + aO[1]);
      async_load16(bP[0], nb + bO[0]); async_load16(bP[1], nb + bO[1]);
      aP[0] += 64; aP[1] += 64; bP[0] += 64; bP[1] += 64;
    }
    const char* cbuf = lds + cur * 16384;
    const char* aF = cbuf + aFo;
    const char* bF = cbuf + bFo;
    bf16x8 av[4];
#pragma unroll
    for (int rt = 0; rt < 4; ++rt) av[rt] = *(const bf16x8*)(aF + rt * 1024);
#pragma unroll
    for (int ct = 0; ct < 4; ++ct) {
      bf16x8 bv = *(const bf16x8*)(bF + ct * 1024);
#pragma unroll
      for (int rt = 0; rt < 4; ++rt)
        acc[rt][ct] = __builtin_amdgcn_mfma_f32_16x16x32_bf16(av[rt], bv, acc[rt][ct], 0, 0, 0);
    }
    __syncthreads();   // drains next-tile DMA + orders buffer reuse
  }

  // epilogue: h = relu((acc + u - m*G)*invs + B); partial text dots + ||h||^2
  // slot = cb*2 + (w&1): this wave's col-half is private -> plain stores.
  int slot = cb * 2 + (w & 1);
#pragma unroll
  for (int rt = 0; rt < 4; ++rt) {
#pragma unroll
    for (int reg = 0; reg < 4; ++reg) {
      int ml = wr + rt * 16 + quad * 4 + reg;
      float rm = rowM[ml], ris = rowIS[ml];
      float p[9] = {};
#pragma unroll
      for (int ct = 0; ct < 4; ++ct) {
        int nl = wc + ct * 16 + lc;
        float h = fmaf(acc[rt][ct][reg] + uArr[nl] - rm * gArr[nl], ris, bArr[nl]);
        h = fmaxf(h, 0.f);
        p[8] = fmaf(h, h, p[8]);
#pragma unroll
        for (int k = 0; k < 8; ++k)
          p[k] = fmaf(h, textL[k * 128 + nl], p[k]);
      }
#pragma unroll
      for (int off = 1; off < 16; off <<= 1) {
#pragma unroll
        for (int k = 0; k < 9; ++k) p[k] += __shfl_xor(p[k], off);
      }
      if (lc == 0) {
        float* Lg = (float*)(ws + OFF_LOG) +
                    ((((size_t)l * 8192 + m0 + ml) * 8 + slot) << 4);
#pragma unroll
        for (int k = 0; k < 9; ++k) Lg[k] = p[k];
      }
    }
  }
}

// ================= finishK: one wave per row (2048 blocks), shfl-reduce slots ====
__global__ __launch_bounds__(256) void finishK(const char* ws, const float* lsc,
                                               float* out) {
  int t = threadIdx.x, wv = t >> 6, lane = t & 63;
  int row = blockIdx.x * 4 + wv;
  int s = lane >> 3, k = lane & 7;
  float scale = fmaxf(lsc[0], 1e-4f) * 0.04419417382415922f;  // 1/sqrt(512)
  float x[4];
#pragma unroll
  for (int l = 0; l < 4; ++l) {
    const float* Lg = (const float*)(ws + OFF_LOG) + (((size_t)l * 8192 + row) << 7);
    float d = Lg[s * 16 + k];
    float n = Lg[s * 16 + 8];
#pragma unroll
    for (int off = 8; off < 64; off <<= 1) {
      d += __shfl_xor(d, off);
      n += __shfl_xor(n, off);
    }
    x[l] = d * (scale / fmaxf(sqrtf(n), 1e-12f));
  }
  if (s == 0) {  // lanes 0..7 hold the reduced values for k=0..7
    float mx = fmaxf(fmaxf(x[0], x[1]), fmaxf(x[2], x[3]));
    float e0 = __expf(x[0] - mx), e1 = __expf(x[1] - mx);
    float e2 = __expf(x[2] - mx), e3 = __expf(x[3] - mx);
    float inv = 1.0f / (e0 + e1 + e2 + e3);
    ((float4*)out)[(size_t)row * 8 + k] = make_float4(e0 * inv, e1 * inv, e2 * inv, e3 * inv);
  }
}

extern "C" void kernel_launch(void* const* d_in, const int* in_sizes, int n_in,
                              void* d_out, int out_size, void* d_ws, size_t ws_size,
                              hipStream_t stream) {
  (void)n_in; (void)out_size;
  if (ws_size < (size_t)WS_TOTAL) return;  // loud failure: output stays poisoned
  char* ws = (char*)d_ws;
  bool dict = (in_sizes[1] == 64 * 256);
  PrepArgs pa;
  for (int l = 0; l < 4; ++l) {
    if (dict) {
      pa.pooled[l] = (const float*)d_in[6 * l + 0];
      pa.proto[l]  = (const float*)d_in[6 * l + 1];
      pa.g[l]      = (const float*)d_in[6 * l + 2];
      pa.beta[l]   = (const float*)d_in[6 * l + 3];
      pa.W[l]      = (const float*)d_in[6 * l + 4];
      pa.bias[l]   = (const float*)d_in[6 * l + 5];
    } else {
      pa.pooled[l] = (const float*)d_in[l];
      pa.proto[l]  = (const float*)d_in[4 + l];
      pa.g[l]      = (const float*)d_in[8 + l];
      pa.beta[l]   = (const float*)d_in[12 + l];
      pa.W[l]      = (const float*)d_in[16 + l];
      pa.bias[l]   = (const float*)d_in[20 + l];
    }
  }
  pa.text = (const float*)d_in[24];
  pa.lsc = (const float*)d_in[25];
  pa.ws = ws;

  // zero the atomic accumulators (U/GG/BB/SCAL; LOG needs no zeroing — all
  // slots are fully written by exactly one producer)
  hipMemsetAsync(ws + OFF_U, 0, 3 * 8192 + 256, stream);

  prep<<<4321, 256, 0, stream>>>(pa);

  G2Args g2;
  g2.ws = ws;
  for (int l = 0; l < 4; ++l) g2.bias[l] = pa.bias[l];
  gemm2<<<1024, 256, 0, stream>>>(g2);
  finishK<<<2048, 256, 0, stream>>>(ws, pa.lsc, (float*)d_out);
}

// Round 12
// 267.279 us; speedup vs baseline: 1.0459x; 1.0377x over previous
//
#include <hip/hip_runtime.h>
#include <stdint.h>

typedef __bf16 bf16x8 __attribute__((ext_vector_type(8)));
typedef float f32x4 __attribute__((ext_vector_type(4)));

// ---- workspace byte offsets ----
#define OFF_GWT   62914560u    // (g*W)^T bf16 per level [512][C]
#define OFF_LOG   66846720u    // f32 [4][8192][8][16]: private partial slots (no atomics)
#define OFF_TEXT  100663296u   // 4096 f32 normalized text
#define OFF_U     100679680u   // 4*512 f32 (zeroed, atomic-accumulated)
#define OFF_GG    100687872u
#define OFF_BB    100696064u
#define OFF_SCAL  100704256u   // [0..3] sproto, [4..7] sqproto (zeroed)
#define WS_TOTAL  100719872u

__host__ __device__ __forceinline__ size_t gwt_off(int l) {
  return (size_t)262144u * (size_t)((1u << l) - 1u);
}

__device__ __forceinline__ unsigned short f2bf(float x) {
  return (unsigned short)((__float_as_uint(x) + 0x8000u) >> 16);
}
__device__ __forceinline__ unsigned pack2(float a, float b) {
  return ((__float_as_uint(a) + 0x8000u) >> 16) |
         ((__float_as_uint(b) + 0x8000u) & 0xffff0000u);
}
__device__ __forceinline__ void async_load16(const void* g, void* l) {
  __builtin_amdgcn_global_load_lds((const __attribute__((address_space(1))) void*)g,
                                   (__attribute__((address_space(3))) void*)l,
                                   16, 0, 0);
}

struct PrepArgs {
  const float* pooled[4];
  const float* proto[4];
  const float* W[4];
  const float* g[4];
  const float* beta[4];
  const float* bias[4];
  const float* text;
  const float* lsc;
  char* ws;
};

// ================= prep: wtrans (bids 0..479) + text (bid 480) =================
// aconv is GONE — the f32->bf16 A-conversion + row stats are fused into gemm2.
__global__ __launch_bounds__(256) void prep(PrepArgs A) {
  __shared__ unsigned short tile[128][66];     // padded: 2-way-only banking
  __shared__ float redG[4][128], redB[4][128], redU[4][128];
  __shared__ float gsh[64], bsh[64], psh[64];
  __shared__ float redP[4][64];
  int t = threadIdx.x, bid = blockIdx.x;
  int w = t >> 6, lane = t & 63;

  if (bid == 480) {
    // ---- text l2norm: 8 rows x 512, 32 lanes/row ----
    int row = t >> 5, l32 = t & 31;
    const float* tr = A.text + row * 512 + l32;
    float v[16];
    float s = 0.f;
#pragma unroll
    for (int i = 0; i < 16; ++i) {
      v[i] = tr[32 * i];
      s = fmaf(v[i], v[i], s);
    }
#pragma unroll
    for (int off = 1; off < 32; off <<= 1) s += __shfl_xor(s, off);
    float inv = 1.0f / fmaxf(sqrtf(s), 1e-12f);
    float* tf = (float*)(A.ws + OFF_TEXT) + row * 512 + l32;
#pragma unroll
    for (int i = 0; i < 16; ++i) tf[32 * i] = v[i] * inv;
    return;
  }

  // ---------------- wtrans path (bids 0..479) ----------------
  int l, idl;
  if (bid < 256)      { l = 3; idl = bid; }
  else if (bid < 384) { l = 2; idl = bid - 256; }
  else if (bid < 448) { l = 1; idl = bid - 384; }
  else                { l = 0; idl = bid - 448; }
  int C = 256 << l;
  int sid = idl >> 2, dchunk = idl & 3;
  int j0 = sid * 64, d0 = dchunk * 128;
  bool top = (j0 < C);
  int L = lane;
  float* scal = (float*)(A.ws + OFF_SCAL);

  if (t < 64) {
    gsh[t] = A.g[l][j0 + t];
    bsh[t] = A.beta[l][j0 + t];
  }
  if (!top) {
    const float* pr = A.proto[l];
    int cb0 = j0 - C;
    float s = 0.f;
#pragma unroll
    for (int r = 0; r < 16; ++r) s += pr[(size_t)(w * 16 + r) * C + cb0 + L];
    redP[w][L] = s;
  }
  __syncthreads();
  if (!top) {
    if (t < 64) {
      float pmv = (redP[0][t] + redP[1][t] + redP[2][t] + redP[3][t]) * (1.0f / 64.0f);
      psh[t] = pmv * gsh[t];
      if (dchunk == 0) {
        float s1 = pmv, s2 = pmv * pmv;
#pragma unroll
        for (int off = 1; off < 64; off <<= 1) {
          s1 += __shfl_xor(s1, off);
          s2 += __shfl_xor(s2, off);
        }
        if (t == 0) {
          atomicAdd(&scal[l], s1);
          atomicAdd(&scal[4 + l], s2);
        }
      }
    }
    __syncthreads();
  }

  const float* W = A.W[l];
  float2 v[16];
#pragma unroll
  for (int r = 0; r < 16; ++r) {
    int j = j0 + w * 16 + r;
    v[r] = *(const float2*)(W + (size_t)j * 512 + d0 + 2 * L);
  }
  float gp0 = 0.f, gp1 = 0.f, bp0 = 0.f, bp1 = 0.f, up0 = 0.f, up1 = 0.f;
#pragma unroll
  for (int r = 0; r < 16; ++r) {
    int jl = w * 16 + r;
    float g = gsh[jl], b = bsh[jl];
    gp0 = fmaf(g, v[r].x, gp0); gp1 = fmaf(g, v[r].y, gp1);
    bp0 = fmaf(b, v[r].x, bp0); bp1 = fmaf(b, v[r].y, bp1);
    if (top) {
      tile[2 * L][jl] = f2bf(g * v[r].x);
      tile[2 * L + 1][jl] = f2bf(g * v[r].y);
    } else {
      float p = psh[jl];
      up0 = fmaf(p, v[r].x, up0); up1 = fmaf(p, v[r].y, up1);
    }
  }
  redG[w][2 * L] = gp0; redG[w][2 * L + 1] = gp1;
  redB[w][2 * L] = bp0; redB[w][2 * L + 1] = bp1;
  if (!top) { redU[w][2 * L] = up0; redU[w][2 * L + 1] = up1; }
  __syncthreads();

  if (t < 128) {
    int d = l * 512 + d0 + t;
    float G = redG[0][t] + redG[1][t] + redG[2][t] + redG[3][t];
    float B = redB[0][t] + redB[1][t] + redB[2][t] + redB[3][t];
    atomicAdd(&((float*)(A.ws + OFF_GG))[d], G);
    atomicAdd(&((float*)(A.ws + OFF_BB))[d], B);
    if (!top) {
      float U = redU[0][t] + redU[1][t] + redU[2][t] + redU[3][t];
      atomicAdd(&((float*)(A.ws + OFF_U))[d], U);
    }
  }
  if (top) {
    unsigned short* gwT = (unsigned short*)(A.ws + OFF_GWT + gwt_off(l));
    int d = t >> 1, jh = (t & 1) * 32;
    const unsigned* trow = (const unsigned*)&tile[d][jh];  // 4B-aligned
    uint4 q0 = make_uint4(trow[0], trow[1], trow[2], trow[3]);
    uint4 q1 = make_uint4(trow[4], trow[5], trow[6], trow[7]);
    uint4 q2 = make_uint4(trow[8], trow[9], trow[10], trow[11]);
    uint4 q3 = make_uint4(trow[12], trow[13], trow[14], trow[15]);
    uint4* dst = (uint4*)(gwT + (size_t)(d0 + d) * C + j0 + jh);
    dst[0] = q0; dst[1] = q1; dst[2] = q2; dst[3] = q3;
  }
}

// ================= gemm2: fused A-convert + GEMM, dbuf, balanced XCD =============
// R3-redux with the three fixes that were missing then:
//  (1) balanced XCD map (R8): cb-siblings co-XCD -> pooled A panel L2-resident,
//      FETCH ~145MB not 250 (R4's 240us was the IMBALANCED map, not this design).
//  (2) dbuf single-barrier step: pack-VALU + f32 loads sit in the same interval
//      as MFMA (VALU pipe only 22% busy) — NOT sched_barrier-pinned like R3.
//  (3) ping-pong named reg sets E/O, 2x-unrolled loop (rule #20: no runtime
//      reg-array indexing). Row sums/sumsq accumulate during pack; rowM/rowIS
//      computed post-loop from scal. aconv/ABF/STAT deleted.
// LDS: A0@0 A1@8K B0@16K B1@24K misc@32K. Swizzle: slot s of row r holds
// granule s^((r>>1)&3); A source granule pre-swizzled (writes stay linear t*16);
// B DMA source pre-swizzled (linear dest, rule #21); reads use matching XOR.
struct G2Args {
  char* ws;
  const float* pooled[4];
  const float* bias[4];
};

__device__ __forceinline__ void packStats(const f32x4& a0, const f32x4& a1,
                                          const f32x4& a2, const f32x4& a3,
                                          char* d0, char* d1,
                                          float& s1a, float& s2a,
                                          float& s1b, float& s2b) {
  *(uint4*)d0 = make_uint4(pack2(a0[0], a0[1]), pack2(a0[2], a0[3]),
                           pack2(a1[0], a1[1]), pack2(a1[2], a1[3]));
  *(uint4*)d1 = make_uint4(pack2(a2[0], a2[1]), pack2(a2[2], a2[3]),
                           pack2(a3[0], a3[1]), pack2(a3[2], a3[3]));
  s1a += ((a0[0] + a0[1]) + (a0[2] + a0[3])) + ((a1[0] + a1[1]) + (a1[2] + a1[3]));
  s2a = fmaf(a0[0], a0[0], s2a); s2a = fmaf(a0[1], a0[1], s2a);
  s2a = fmaf(a0[2], a0[2], s2a); s2a = fmaf(a0[3], a0[3], s2a);
  s2a = fmaf(a1[0], a1[0], s2a); s2a = fmaf(a1[1], a1[1], s2a);
  s2a = fmaf(a1[2], a1[2], s2a); s2a = fmaf(a1[3], a1[3], s2a);
  s1b += ((a2[0] + a2[1]) + (a2[2] + a2[3])) + ((a3[0] + a3[1]) + (a3[2] + a3[3]));
  s2b = fmaf(a2[0], a2[0], s2b); s2b = fmaf(a2[1], a2[1], s2b);
  s2b = fmaf(a2[2], a2[2], s2b); s2b = fmaf(a2[3], a2[3], s2b);
  s2b = fmaf(a3[0], a3[0], s2b); s2b = fmaf(a3[1], a3[1], s2b);
  s2b = fmaf(a3[2], a3[2], s2b); s2b = fmaf(a3[3], a3[3], s2b);
}

__global__ __launch_bounds__(256, 3) void gemm2(G2Args A) {
  __shared__ __align__(16) char lds[39424];   // A0 A1 B0 B1 (8K each) | misc
  char* ws = A.ws;
  int t = threadIdx.x;
  int xcd = blockIdx.x & 7;        // round-robin XCD assumption (perf-only)
  int j   = blockIdx.x >> 3;       // 0..127 within this XCD's share
  int l   = 3 - (j >> 5);          // 32 blocks of each level per XCD (balanced)
  int jj  = j & 31;
  int rb  = xcd * 8 + (jj >> 2);
  int cb  = jj & 3;
  int C = 256 << l;
  int nst = C >> 5;
  int m0 = rb * 128, n0 = cb * 128;

  float* uArr  = (float*)(lds + 32768);
  float* gArr  = (float*)(lds + 33280);
  float* bArr  = (float*)(lds + 33792);
  float* rowM  = (float*)(lds + 34304);
  float* rowIS = (float*)(lds + 34816);
  float* textL = (float*)(lds + 35328);   // [8][128]
  const float* scal = (const float*)(ws + OFF_SCAL);

  if (t < 128) {
    int idx = l * 512 + n0 + t;
    uArr[t] = ((const float*)(ws + OFF_U))[idx];
    gArr[t] = ((const float*)(ws + OFF_GG))[idx];
    bArr[t] = ((const float*)(ws + OFF_BB))[idx] + A.bias[l][n0 + t];
  }
  {
    const float* tf = (const float*)(ws + OFF_TEXT);
#pragma unroll
    for (int i = 0; i < 4; ++i) {
      int idx = t + 256 * i;          // 0..1023 -> [8][128]
      textL[idx] = tf[(idx >> 7) * 512 + n0 + (idx & 127)];
    }
  }

  int w = t >> 6, lane = t & 63, quad = lane >> 4, lc = lane & 15;

  // ---- A staging: thread owns rows rA and 64+rA, source granule pre-swizzled ----
  int rA = t >> 2, sA = t & 3;
  int gq = sA ^ ((rA >> 1) & 3);
  const float* aG0 = A.pooled[l] + (size_t)(m0 + rA) * C + gq * 8;
  const float* aG1 = aG0 + (size_t)64 * C;
  char* aW0 = lds + (t << 4);        // rA*64 + sA*16 == t*16 (linear, conflict-free)
  char* aW1 = aW0 + 4096;

  // ---- B staging (DMA, source-swizzled, linear dest) ----
  const char* Bw = ws + OFF_GWT + gwt_off(l);
  const char* bP[2]; int bO[2];
#pragma unroll
  for (int i = 0; i < 2; ++i) {
    int li = i * 256 + t;
    int rr = li >> 2, kq = li & 3;
    int sw = kq ^ ((rr >> 1) & 3);
    bP[i] = Bw + ((size_t)(n0 + rr) * C + sw * 8) * 2;
    bO[i] = i * 4096 + w * 1024;     // within-buffer (lane*16 implicit)
  }

  // ---- fragment read offsets (match the staging swizzle) ----
  int wr = (w >> 1) * 64, wc = (w & 1) * 64;
  int arow = wr + lc, brow = wc + lc;
  int aFo = arow * 64 + (quad ^ ((arow >> 1) & 3)) * 16;
  int bFo = brow * 64 + (quad ^ ((brow >> 1) & 3)) * 16;

  f32x4 acc[4][4] = {};
  float s1a = 0.f, s2a = 0.f, s1b = 0.f, s2b = 0.f;
  f32x4 e0, e1, e2, e3, o0, o1, o2, o3;

  auto mfmaStep = [&](const char* ab, const char* bb) {
    bf16x8 av[4];
#pragma unroll
    for (int rt = 0; rt < 4; ++rt) av[rt] = *(const bf16x8*)(ab + aFo + rt * 1024);
#pragma unroll
    for (int ct = 0; ct < 4; ++ct) {
      bf16x8 bv = *(const bf16x8*)(bb + bFo + ct * 1024);
#pragma unroll
      for (int rt = 0; rt < 4; ++rt)
        acc[rt][ct] = __builtin_amdgcn_mfma_f32_16x16x32_bf16(av[rt], bv, acc[rt][ct], 0, 0, 0);
    }
  };

  // ---- prologue: tile0 -> buf0; preload tile1 regs ----
  e0 = *(const f32x4*)aG0; e1 = *(const f32x4*)(aG0 + 4);
  e2 = *(const f32x4*)aG1; e3 = *(const f32x4*)(aG1 + 4);
  aG0 += 32; aG1 += 32;
  async_load16(bP[0], lds + 16384 + bO[0]);
  async_load16(bP[1], lds + 16384 + bO[1]);
  bP[0] += 64; bP[1] += 64;
  packStats(e0, e1, e2, e3, aW0, aW1, s1a, s2a, s1b, s2b);
  o0 = *(const f32x4*)aG0; o1 = *(const f32x4*)(aG0 + 4);
  o2 = *(const f32x4*)aG1; o3 = *(const f32x4*)(aG1 + 4);
  aG0 += 32; aG1 += 32;
  __syncthreads();   // buf0 ready (B DMA drained, A ds_writes ordered)

  for (int k = 0; k < nst; k += 2) {
    // ---- EVEN step: compute tile k from buf0; stage tile k+1 -> buf1 ----
    if (k + 1 < nst) {
      async_load16(bP[0], lds + 24576 + bO[0]);
      async_load16(bP[1], lds + 24576 + bO[1]);
      bP[0] += 64; bP[1] += 64;
      packStats(o0, o1, o2, o3, lds + 8192 + (t << 4), lds + 8192 + 4096 + (t << 4),
                s1a, s2a, s1b, s2b);
      if (k + 2 < nst) {
        e0 = *(const f32x4*)aG0; e1 = *(const f32x4*)(aG0 + 4);
        e2 = *(const f32x4*)aG1; e3 = *(const f32x4*)(aG1 + 4);
        aG0 += 32; aG1 += 32;
      }
    }
    mfmaStep(lds, lds + 16384);
    __syncthreads();
    if (k + 1 >= nst) break;
    // ---- ODD step: compute tile k+1 from buf1; stage tile k+2 -> buf0 ----
    if (k + 2 < nst) {
      async_load16(bP[0], lds + 16384 + bO[0]);
      async_load16(bP[1], lds + 16384 + bO[1]);
      bP[0] += 64; bP[1] += 64;
      packStats(e0, e1, e2, e3, aW0, aW1, s1a, s2a, s1b, s2b);
      if (k + 3 < nst) {
        o0 = *(const f32x4*)aG0; o1 = *(const f32x4*)(aG0 + 4);
        o2 = *(const f32x4*)aG1; o3 = *(const f32x4*)(aG1 + 4);
        aG0 += 32; aG1 += 32;
      }
    }
    mfmaStep(lds + 8192, lds + 24576);
    __syncthreads();
  }

  // ---- finish row stats: reduce the 4 granule partials per row ----
#pragma unroll
  for (int off = 1; off < 4; off <<= 1) {
    s1a += __shfl_xor(s1a, off); s2a += __shfl_xor(s2a, off);
    s1b += __shfl_xor(s1b, off); s2b += __shfl_xor(s2b, off);
  }
  if ((t & 3) == 0) {
    float inv2C = 1.0f / (float)(2 * C);
    float spro = scal[l], sqpro = scal[4 + l];
    float mra = (s1a + spro) * inv2C;
    rowM[rA] = mra;
    rowIS[rA] = rsqrtf((s2a + sqpro) * inv2C - mra * mra + 1e-5f);
    float mrb = (s1b + spro) * inv2C;
    rowM[64 + rA] = mrb;
    rowIS[64 + rA] = rsqrtf((s2b + sqpro) * inv2C - mrb * mrb + 1e-5f);
  }
  __syncthreads();

  // ---- epilogue: h = relu((acc + u - m*G)*invs + B); partial dots + ||h||^2 ----
  int slot = cb * 2 + (w & 1);
#pragma unroll
  for (int rt = 0; rt < 4; ++rt) {
#pragma unroll
    for (int reg = 0; reg < 4; ++reg) {
      int ml = wr + rt * 16 + quad * 4 + reg;
      float rm = rowM[ml], ris = rowIS[ml];
      float p[9] = {};
#pragma unroll
      for (int ct = 0; ct < 4; ++ct) {
        int nl = wc + ct * 16 + lc;
        float h = fmaf(acc[rt][ct][reg] + uArr[nl] - rm * gArr[nl], ris, bArr[nl]);
        h = fmaxf(h, 0.f);
        p[8] = fmaf(h, h, p[8]);
#pragma unroll
        for (int k = 0; k < 8; ++k)
          p[k] = fmaf(h, textL[k * 128 + nl], p[k]);
      }
#pragma unroll
      for (int off = 1; off < 16; off <<= 1) {
#pragma unroll
        for (int k = 0; k < 9; ++k) p[k] += __shfl_xor(p[k], off);
      }
      if (lc == 0) {
        float* Lg = (float*)(ws + OFF_LOG) +
                    ((((size_t)l * 8192 + m0 + ml) * 8 + slot) << 4);
#pragma unroll
        for (int k = 0; k < 9; ++k) Lg[k] = p[k];
      }
    }
  }
}

// ================= finishK: one wave per row (2048 blocks), shfl-reduce slots ====
__global__ __launch_bounds__(256) void finishK(const char* ws, const float* lsc,
                                               float* out) {
  int t = threadIdx.x, wv = t >> 6, lane = t & 63;
  int row = blockIdx.x * 4 + wv;
  int s = lane >> 3, k = lane & 7;
  float scale = fmaxf(lsc[0], 1e-4f) * 0.04419417382415922f;  // 1/sqrt(512)
  float x[4];
#pragma unroll
  for (int l = 0; l < 4; ++l) {
    const float* Lg = (const float*)(ws + OFF_LOG) + (((size_t)l * 8192 + row) << 7);
    float d = Lg[s * 16 + k];
    float n = Lg[s * 16 + 8];
#pragma unroll
    for (int off = 8; off < 64; off <<= 1) {
      d += __shfl_xor(d, off);
      n += __shfl_xor(n, off);
    }
    x[l] = d * (scale / fmaxf(sqrtf(n), 1e-12f));
  }
  if (s == 0) {  // lanes 0..7 hold the reduced values for k=0..7
    float mx = fmaxf(fmaxf(x[0], x[1]), fmaxf(x[2], x[3]));
    float e0 = __expf(x[0] - mx), e1 = __expf(x[1] - mx);
    float e2 = __expf(x[2] - mx), e3 = __expf(x[3] - mx);
    float inv = 1.0f / (e0 + e1 + e2 + e3);
    ((float4*)out)[(size_t)row * 8 + k] = make_float4(e0 * inv, e1 * inv, e2 * inv, e3 * inv);
  }
}

extern "C" void kernel_launch(void* const* d_in, const int* in_sizes, int n_in,
                              void* d_out, int out_size, void* d_ws, size_t ws_size,
                              hipStream_t stream) {
  (void)n_in; (void)out_size;
  if (ws_size < (size_t)WS_TOTAL) return;  // loud failure: output stays poisoned
  char* ws = (char*)d_ws;
  bool dict = (in_sizes[1] == 64 * 256);
  PrepArgs pa;
  for (int l = 0; l < 4; ++l) {
    if (dict) {
      pa.pooled[l] = (const float*)d_in[6 * l + 0];
      pa.proto[l]  = (const float*)d_in[6 * l + 1];
      pa.g[l]      = (const float*)d_in[6 * l + 2];
      pa.beta[l]   = (const float*)d_in[6 * l + 3];
      pa.W[l]      = (const float*)d_in[6 * l + 4];
      pa.bias[l]   = (const float*)d_in[6 * l + 5];
    } else {
      pa.pooled[l] = (const float*)d_in[l];
      pa.proto[l]  = (const float*)d_in[4 + l];
      pa.g[l]      = (const float*)d_in[8 + l];
      pa.beta[l]   = (const float*)d_in[12 + l];
      pa.W[l]      = (const float*)d_in[16 + l];
      pa.bias[l]   = (const float*)d_in[20 + l];
    }
  }
  pa.text = (const float*)d_in[24];
  pa.lsc = (const float*)d_in[25];
  pa.ws = ws;

  // zero the atomic accumulators (U/GG/BB/SCAL; LOG needs no zeroing — all
  // slots are fully written by exactly one producer)
  hipMemsetAsync(ws + OFF_U, 0, 3 * 8192 + 256, stream);

  prep<<<481, 256, 0, stream>>>(pa);

  G2Args g2;
  g2.ws = ws;
  for (int l = 0; l < 4; ++l) {
    g2.pooled[l] = pa.pooled[l];
    g2.bias[l] = pa.bias[l];
  }
  gemm2<<<1024, 256, 0, stream>>>(g2);
  finishK<<<2048, 256, 0, stream>>>(ws, pa.lsc, (float*)d_out);
}